// Round 3
// baseline (10612.401 us; speedup 1.0000x reference)
//
#include <hip/hip_runtime.h>
#include <hip/hip_fp16.h>

// LP=500, LQ=64, B=64, D=256, H=150
#define LP 500

typedef _Float16 h2f __attribute__((ext_vector_type(2)));
typedef _Float16 h8f __attribute__((ext_vector_type(8)));

// ---------------- workspace layout (float slots) ----------------
// Column-major f16-pair weight layouts: W2[k2][M] where k2 = pair index along
// the reduction dim, M = padded output count. float4 at (k2, 4m) = 4 outputs.
constexpr size_t OFF_WVH2 = 0;         // [76][608] h2f: cols 0..149 Wv rows, 150..599 Whh rows, pad 0
constexpr size_t OFF_WGF2 = 46208;     // [128][512] h2f folded Wg cc-part
constexpr size_t OFF_WIH2 = 111744;    // [256][452] h2f Wih (cols 450,451 zero)
constexpr size_t OFF_WPF  = 227456;    // [150][256] f32 folded Wp
constexpr size_t OFF_WQF  = 265856;    // [150][256] f32 folded Wq
constexpr size_t OFF_WUQ  = 304256;    // [64][64][150] f32 Wuq[q][b][h]
constexpr size_t OFF_P1   = 918656;    // [500][64][150] f32  (WG1 [512][256] f32 ALIASED here pre-P1)
constexpr size_t OFF_WG1  = OFF_P1;    // alias: consumed by Gu GEMM before P1 GEMM overwrites
constexpr size_t OFF_GUH  = 5718656;   // [500][64][512] f16 Gu
constexpr size_t OFF_UPT  = 13910656;  // [500][256][64] f32
constexpr size_t OFF_UQT  = 22102656;  // [64][256][64] f32   (UqT2 [64][32][256] h2f ALIASED here post-GEMM)
constexpr size_t OFF_UQT2 = OFF_UQT;   // alias: written after Wuq GEMM consumes UQT
constexpr size_t WS_FLOATS = 23151232; // 92.6 MB (<= R1/R2's 93.1 MB proven available)

// ---------------- helpers ----------------
__device__ __forceinline__ float fast_rcp(float x) { return __builtin_amdgcn_rcpf(x); }
__device__ __forceinline__ float sigm(float x)   { return fast_rcp(1.f + __expf(-x)); }
__device__ __forceinline__ float tanh_f(float x) { return 1.f - 2.f * fast_rcp(1.f + __expf(2.f * x)); }

// ---------------- precompute: weight folds + f16 column-major packs ----------------
__global__ __launch_bounds__(256) void k_prep(const float* __restrict__ Wp, const float* __restrict__ Wq,
                                              const float* __restrict__ Wg, const float* __restrict__ Wv,
                                              const float* __restrict__ Whh, const float* __restrict__ Wih,
                                              float* __restrict__ ws) {
    int i = blockIdx.x * 256 + threadIdx.x;
    if (i < 46208) {  // WVH2 [76][608]
        int k2 = i / 608, m = i - k2 * 608;
        float lo = 0.f, hi = 0.f;
        if (k2 < 75 && m < 600) {
            if (m < 150) { lo = Wv[m * 150 + 2 * k2]; hi = Wv[m * 150 + 2 * k2 + 1]; }
            else { int mm = m - 150; lo = Whh[mm * 150 + 2 * k2]; hi = Whh[mm * 150 + 2 * k2 + 1]; }
        }
        ((h2f*)(ws + OFF_WVH2))[i] = h2f{(_Float16)lo, (_Float16)hi};
        return;
    }
    i -= 46208;
    if (i < 65536) {  // WGF2 [128][512]
        int k2 = i >> 9, j = i & 511;
        int d = 2 * k2;
        size_t r = (size_t)(512 + j) * 1024;
        float lo = Wg[r + 512 + d] + Wg[r + 768 + d];
        float hi = Wg[r + 512 + d + 1] + Wg[r + 768 + d + 1];
        ((h2f*)(ws + OFF_WGF2))[i] = h2f{(_Float16)lo, (_Float16)hi};
        return;
    }
    i -= 65536;
    if (i < 115712) {  // WIH2 [256][452]
        int k2 = i / 452, m = i - k2 * 452;
        float lo = 0.f, hi = 0.f;
        if (m < 450) { lo = Wih[m * 512 + 2 * k2]; hi = Wih[m * 512 + 2 * k2 + 1]; }
        ((h2f*)(ws + OFF_WIH2))[i] = h2f{(_Float16)lo, (_Float16)hi};
        return;
    }
    i -= 115712;
    if (i < 38400) { int h = i >> 8, d = i & 255; ws[OFF_WPF + i] = Wp[h * 512 + d] + Wp[h * 512 + 256 + d]; return; }
    i -= 38400;
    if (i < 38400) { int h = i >> 8, d = i & 255; ws[OFF_WQF + i] = Wq[h * 512 + d] + Wq[h * 512 + 256 + d]; return; }
    i -= 38400;
    if (i < 131072) { int j = i >> 8, d = i & 255; size_t r = (size_t)(512 + j) * 1024; ws[OFF_WG1 + i] = Wg[r + d] + Wg[r + 256 + d]; return; }
}

// transpose X[t][64][256] -> XT[t][256][64], one block per t
__global__ __launch_bounds__(256) void k_tr(const float* __restrict__ X, float* __restrict__ XT) {
    __shared__ float tile[64][65];
    size_t base = (size_t)blockIdx.x * 16384;
    for (int ph = 0; ph < 4; ++ph) {
        for (int i = threadIdx.x; i < 4096; i += 256) {
            int b = i >> 6, dl = i & 63;
            tile[b][dl] = X[base + (size_t)b * 256 + ph * 64 + dl];
        }
        __syncthreads();
        for (int i = threadIdx.x; i < 4096; i += 256) {
            int d = i >> 6, bl = i & 63;
            XT[base + (size_t)(ph * 64 + d) * 64 + bl] = tile[bl][d];
        }
        __syncthreads();
    }
}

// acc[h,b] = sum_d XT[t,d,b]*Wf[h,d]; writes out[t][b][Hrows] as f32 or f16
__global__ __launch_bounds__(256) void k_gemm(const float* __restrict__ XT, const float* __restrict__ Wf,
                                              float* __restrict__ outF, _Float16* __restrict__ outH,
                                              int Hrows, int tilesPerT) {
    __shared__ float OL[64 * 33];
    int bidx = blockIdx.x;
    int t = bidx / tilesPerT, tile = bidx - t * tilesPerT;
    int w = threadIdx.x >> 6, lane = threadIdx.x & 63;
    int h0 = __builtin_amdgcn_readfirstlane(tile * 32 + w * 8);
    const float* x = XT + (size_t)t * 16384;
    float acc[8];
    const float* wr[8];
#pragma unroll
    for (int r = 0; r < 8; ++r) {
        int hr = h0 + r; if (hr >= Hrows) hr = Hrows - 1;
        wr[r] = Wf + (size_t)hr * 256;
        acc[r] = 0.f;
    }
    for (int d = 0; d < 256; d += 4) {
        float cv0 = x[(d + 0) * 64 + lane];
        float cv1 = x[(d + 1) * 64 + lane];
        float cv2 = x[(d + 2) * 64 + lane];
        float cv3 = x[(d + 3) * 64 + lane];
#pragma unroll
        for (int r = 0; r < 8; ++r) {
            float4 wv = *(const float4*)(wr[r] + d);
            acc[r] += cv0 * wv.x + cv1 * wv.y + cv2 * wv.z + cv3 * wv.w;
        }
    }
#pragma unroll
    for (int r = 0; r < 8; ++r) { int hl = w * 8 + r; OL[lane * 33 + hl] = acc[r]; }
    __syncthreads();
    int hbase = tile * 32;
    int nh = Hrows - hbase; if (nh > 32) nh = 32;
    for (int i = threadIdx.x; i < 64 * nh; i += 256) {
        int b = i / nh, hl = i - b * nh;
        float val = OL[b * 33 + hl];
        size_t idx = (size_t)t * 64 * Hrows + (size_t)b * Hrows + hbase + hl;
        if (outF) outF[idx] = val;
        else outH[idx] = (_Float16)val;
    }
}

// UqT2[b][q2][d] = (f16 Uq[2q2][b][d], f16 Uq[2q2+1][b][d])
__global__ __launch_bounds__(256) void k_uqt(const float* __restrict__ Uq, h2f* __restrict__ UqT2) {
    int b = blockIdx.x, d = threadIdx.x;
    for (int q2 = 0; q2 < 32; ++q2) {
        float lo = Uq[(size_t)(2 * q2) * 16384 + b * 256 + d];
        float hi = Uq[(size_t)(2 * q2 + 1) * 16384 + b * 256 + d];
        UqT2[(size_t)b * 8192 + q2 * 256 + d] = h2f{(_Float16)lo, (_Float16)hi};
    }
}

// ---------------- per-batch persistent scan: 64 blocks x 1024 threads ----------------
__global__ __launch_bounds__(1024) void k_scan3(
    const float* __restrict__ V, const float* __restrict__ v0,
    const float* __restrict__ bih, const float* __restrict__ bhh,
    const float* __restrict__ ws, float* __restrict__ out) {
    __shared__ __attribute__((aligned(16))) float red[4096];      // partial-sum scratch (16KB), reused per phase
    __shared__ __attribute__((aligned(16))) _Float16 wuqh[64 * 152];
    __shared__ __attribute__((aligned(16))) _Float16 vh[152];     // v_t f16 (k-padded: [150],[151]=0)
    __shared__ float pbf[152];
    __shared__ float ghf[452];
    __shared__ float Vb[152];
    __shared__ float bihL[452];
    __shared__ float bhhL[452];
    __shared__ float vf[152];
    __shared__ float sa[64];
    __shared__ __attribute__((aligned(8))) h2f sah[32];
    __shared__ float ccf[256];
    __shared__ __attribute__((aligned(8))) h2f cchp[128];
    __shared__ __attribute__((aligned(8))) h2f c_p[256];
    __shared__ float gif[452];

    const int tid = threadIdx.x, b = blockIdx.x;
    const int lane = tid & 63;
    const h2f* Wvh2 = (const h2f*)(ws + OFF_WVH2);
    const h2f* Wgf2 = (const h2f*)(ws + OFF_WGF2);
    const h2f* Wih2 = (const h2f*)(ws + OFF_WIH2);
    const h2f* UqT2b = (const h2f*)(ws + OFF_UQT2) + (size_t)b * 8192;
    const float* WuqG = ws + OFF_WUQ;
    const float* P1 = ws + OFF_P1;
    const _Float16* GuH = (const _Float16*)(ws + OFF_GUH);

    // ---- per-phase static thread assignments (live across the t-loop) ----
    // phase1: M=608 (600 live), M4=152, ks=4, 19 k2 each
    const int p1_ks = tid / 152, p1_mq = tid - p1_ks * 152;      // valid when tid<608
    const h2f* wv_base = Wvh2 + (size_t)(p1_ks * 19) * 608 + 4 * p1_mq;
    // phase2b: M=256, M4=64, ks=8, 4 q2 each
    const int p2_mq = tid & 63, p2_qs = tid >> 6;                 // valid when tid<512
    const h2f* uq_base = UqT2b + (size_t)(p2_qs * 4) * 256 + 4 * p2_mq;
    // phase3: M=512, M4=128, ks=8, 16 k2 each — weights REGISTER-RESIDENT
    const int p3_mq = tid & 127, p3_ks = tid >> 7;
    // phase4: M=452 (450 live), M4=113, ks=8, 32 k2 each
    const int p4_ks = tid / 113, p4_mq = tid - p4_ks * 113;       // valid when tid<904
    const h2f* wih_base = Wih2 + (size_t)(p4_ks * 32) * 452 + 4 * p4_mq;

    // preload ALL of Wgf2 into registers: 1024 threads x 16 h8f = 262KB, no dup
    h8f wgr[16];
#pragma unroll
    for (int i = 0; i < 16; ++i)
        wgr[i] = *(const h8f*)(Wgf2 + (size_t)(p3_ks * 16 + i) * 512 + 4 * p3_mq);

    // ---- one-time per-b LDS init ----
    for (int i = tid; i < 64 * 150; i += 1024) { int q = i / 150, h = i - q * 150; wuqh[q * 152 + h] = (_Float16)WuqG[(size_t)q * 9600 + b * 150 + h]; }
    for (int i = tid; i < 150; i += 1024) { Vb[i] = V[b * 150 + i]; float v = v0[b * 150 + i]; vf[i] = v; vh[i] = (_Float16)v; }
    for (int i = tid; i < 450; i += 1024) { bihL[i] = bih[i]; bhhL[i] = bhh[i]; }
    if (tid < 2) vh[150 + tid] = (_Float16)0.f;
    __syncthreads();

    for (int t = 0; t < LP; ++t) {
        // ---- phase1 partials: 608 threads, [pb|gh](m) = sum_k Wvh[k][m]*v[k] ----
        if (tid < 608) {
            const h2f* vh2 = (const h2f*)vh;
            float a0 = 0.f, a1 = 0.f, a2 = 0.f, a3 = 0.f;
#pragma unroll
            for (int i = 0; i < 19; ++i) {
                h8f w = *(const h8f*)(wv_base + (size_t)i * 608);
                h2f x = vh2[p1_ks * 19 + i];
                a0 = __builtin_amdgcn_fdot2(h2f{w[0], w[1]}, x, a0, false);
                a1 = __builtin_amdgcn_fdot2(h2f{w[2], w[3]}, x, a1, false);
                a2 = __builtin_amdgcn_fdot2(h2f{w[4], w[5]}, x, a2, false);
                a3 = __builtin_amdgcn_fdot2(h2f{w[6], w[7]}, x, a3, false);
            }
            *(float4*)(red + p1_ks * 608 + 4 * p1_mq) = float4{a0, a1, a2, a3};
        }
        __syncthreads();
        if (tid < 600) {  // reduce + epilogue
            float s = red[tid] + red[608 + tid] + red[1216 + tid] + red[1824 + tid];
            if (tid < 150) pbf[tid] = s + P1[(size_t)t * 9600 + b * 150 + tid];
            else ghf[tid - 150] = s + bhhL[tid - 150];
        }
        __syncthreads();
        // ---- phase2a: s[q] = sum_h tanh(pb+wuq)*V, 16 waves x 4 q ----
        {
            int w16 = tid >> 6;
#pragma unroll
            for (int i = 0; i < 4; ++i) {
                int q = w16 * 4 + i;
                float part = 0.f;
                for (int idx = lane; idx < 150; idx += 64)
                    part += tanh_f(pbf[idx] + (float)wuqh[q * 152 + idx]) * Vb[idx];
                part += __shfl_xor(part, 32); part += __shfl_xor(part, 16);
                part += __shfl_xor(part, 8);  part += __shfl_xor(part, 4);
                part += __shfl_xor(part, 2);  part += __shfl_xor(part, 1);
                if (lane == 0) sa[q] = part;
            }
        }
        __syncthreads();
        if (tid < 64) {  // softmax + pack a into h2f pairs
            float s = sa[tid];
            float m = s;
            m = fmaxf(m, __shfl_xor(m, 32)); m = fmaxf(m, __shfl_xor(m, 16));
            m = fmaxf(m, __shfl_xor(m, 8));  m = fmaxf(m, __shfl_xor(m, 4));
            m = fmaxf(m, __shfl_xor(m, 2));  m = fmaxf(m, __shfl_xor(m, 1));
            float e = __expf(s - m);
            float su = e;
            su += __shfl_xor(su, 32); su += __shfl_xor(su, 16); su += __shfl_xor(su, 8);
            su += __shfl_xor(su, 4);  su += __shfl_xor(su, 2);  su += __shfl_xor(su, 1);
            float a = e * fast_rcp(su);
            float an = __shfl_xor(a, 1);
            if ((tid & 1) == 0) sah[tid >> 1] = h2f{(_Float16)a, (_Float16)an};
        }
        __syncthreads();
        // ---- phase2b: cc[d] = sum_q a[q] Uq[q,b,d], 512 threads ----
        if (tid < 512) {
            float a0 = 0.f, a1 = 0.f, a2 = 0.f, a3 = 0.f;
#pragma unroll
            for (int i = 0; i < 4; ++i) {
                h8f u = *(const h8f*)(uq_base + (size_t)i * 256);
                h2f ap = sah[p2_qs * 4 + i];
                a0 = __builtin_amdgcn_fdot2(h2f{u[0], u[1]}, ap, a0, false);
                a1 = __builtin_amdgcn_fdot2(h2f{u[2], u[3]}, ap, a1, false);
                a2 = __builtin_amdgcn_fdot2(h2f{u[4], u[5]}, ap, a2, false);
                a3 = __builtin_amdgcn_fdot2(h2f{u[6], u[7]}, ap, a3, false);
            }
            *(float4*)(red + p2_qs * 256 + 4 * p2_mq) = float4{a0, a1, a2, a3};
        }
        __syncthreads();
        if (tid < 256) {  // reduce + pack cc pairs
            float cc = 0.f;
#pragma unroll
            for (int s8 = 0; s8 < 8; ++s8) cc += red[s8 * 256 + tid];
            ccf[tid] = cc;
            float cn = __shfl_xor(cc, 1);
            if ((tid & 1) == 0) cchp[tid >> 1] = h2f{(_Float16)cc, (_Float16)cn};
        }
        __syncthreads();
        // ---- phase3: g-partials from REGISTER weights, all 1024 threads ----
        {
            float a0 = 0.f, a1 = 0.f, a2 = 0.f, a3 = 0.f;
#pragma unroll
            for (int i = 0; i < 16; ++i) {
                h2f cp = cchp[p3_ks * 16 + i];
                h8f w = wgr[i];
                a0 = __builtin_amdgcn_fdot2(h2f{w[0], w[1]}, cp, a0, false);
                a1 = __builtin_amdgcn_fdot2(h2f{w[2], w[3]}, cp, a1, false);
                a2 = __builtin_amdgcn_fdot2(h2f{w[4], w[5]}, cp, a2, false);
                a3 = __builtin_amdgcn_fdot2(h2f{w[6], w[7]}, cp, a3, false);
            }
            *(float4*)(red + p3_ks * 512 + 4 * p3_mq) = float4{a0, a1, a2, a3};
        }
        __syncthreads();
        if (tid < 512) {  // g reduce + c_ pack
            float s = (float)GuH[(size_t)t * 32768 + b * 512 + tid];
#pragma unroll
            for (int s8 = 0; s8 < 8; ++s8) s += red[s8 * 512 + tid];
            float val = sigm(s) * ccf[tid & 255];
            float vn2 = __shfl_xor(val, 1);
            if ((tid & 1) == 0) c_p[tid >> 1] = h2f{(_Float16)val, (_Float16)vn2};
        }
        __syncthreads();
        // ---- phase4: gi partials, 904 threads ----
        if (tid < 904) {
            float a0 = 0.f, a1 = 0.f, a2 = 0.f, a3 = 0.f;
#pragma unroll
            for (int i = 0; i < 32; ++i) {
                h8f w = *(const h8f*)(wih_base + (size_t)i * 452);
                h2f cp = c_p[p4_ks * 32 + i];
                a0 = __builtin_amdgcn_fdot2(h2f{w[0], w[1]}, cp, a0, false);
                a1 = __builtin_amdgcn_fdot2(h2f{w[2], w[3]}, cp, a1, false);
                a2 = __builtin_amdgcn_fdot2(h2f{w[4], w[5]}, cp, a2, false);
                a3 = __builtin_amdgcn_fdot2(h2f{w[6], w[7]}, cp, a3, false);
            }
            *(float4*)(red + p4_ks * 456 + 4 * p4_mq) = float4{a0, a1, a2, a3};
        }
        __syncthreads();
        if (tid < 450) {
            float s = 0.f;
#pragma unroll
            for (int s8 = 0; s8 < 8; ++s8) s += red[s8 * 456 + tid];
            gif[tid] = s;
        }
        __syncthreads();
        if (tid < 150) {  // GRU combine + state update + output
            float r = sigm(gif[tid] + bihL[tid] + ghf[tid]);
            float z = sigm(gif[150 + tid] + bihL[150 + tid] + ghf[150 + tid]);
            float n = tanh_f(gif[300 + tid] + bihL[300 + tid] + r * ghf[300 + tid]);
            float vn = (1.f - z) * n + z * vf[tid];
            vf[tid] = vn;
            vh[tid] = (_Float16)vn;
            out[(size_t)t * 9600 + b * 150 + tid] = vn;
        }
        __syncthreads();
    }
}

// ---------------- launch ----------------
extern "C" void kernel_launch(void* const* d_in, const int* in_sizes, int n_in,
                              void* d_out, int out_size, void* d_ws, size_t ws_size,
                              hipStream_t stream) {
    const float* Up  = (const float*)d_in[0];
    const float* Uq  = (const float*)d_in[1];
    const float* Wp  = (const float*)d_in[2];
    const float* Wq  = (const float*)d_in[3];
    const float* Wv  = (const float*)d_in[4];
    const float* Wg  = (const float*)d_in[5];
    const float* V   = (const float*)d_in[6];
    const float* v0  = (const float*)d_in[7];
    const float* Wih = (const float*)d_in[8];
    const float* Whh = (const float*)d_in[9];
    const float* bih = (const float*)d_in[10];
    const float* bhh = (const float*)d_in[11];
    float* out = (float*)d_out;
    float* ws = (float*)d_ws;

    if (ws_size < WS_FLOATS * sizeof(float)) return;

    // folds + packs (435,328 items)
    k_prep<<<1701, 256, 0, stream>>>(Wp, Wq, Wg, Wv, Whh, Wih, ws);
    k_tr<<<500, 256, 0, stream>>>(Up, ws + OFF_UPT);
    k_tr<<<64, 256, 0, stream>>>(Uq, ws + OFF_UQT);
    // Gu[t][b][j] = Up[t] @ Wg1^T (f16) — MUST run before P1 GEMM (WG1 aliases P1)
    k_gemm<<<8000, 256, 0, stream>>>(ws + OFF_UPT, ws + OFF_WG1, nullptr, (_Float16*)(ws + OFF_GUH), 512, 16);
    // P1[t][b][h] = Up[t] @ Wpf^T (f32) — overwrites WG1 alias region (done with it)
    k_gemm<<<2500, 256, 0, stream>>>(ws + OFF_UPT, ws + OFF_WPF, ws + OFF_P1, nullptr, 150, 5);
    // Wuq[q][b][h] = Uq[q] @ Wqf^T (f32) — consumes UQT before k_uqt overwrites it
    k_gemm<<<320, 256, 0, stream>>>(ws + OFF_UQT, ws + OFF_WQF, ws + OFF_WUQ, nullptr, 150, 5);
    // UqT2[b][q2][d] f16 pairs — aliases UQT (safe: after Wuq GEMM)
    k_uqt<<<64, 256, 0, stream>>>(Uq, (h2f*)(ws + OFF_UQT2));
    // barrier-free per-batch scan
    k_scan3<<<64, 1024, 0, stream>>>(V, v0, bih, bhh, ws, out);
}

// Round 6
// 10483.104 us; speedup vs baseline: 1.0123x; 1.0123x over previous
//
#include <hip/hip_runtime.h>
#include <hip/hip_fp16.h>

// LP=500, LQ=64, B=64, D=256, H=150
#define LP 500

typedef _Float16 h2f __attribute__((ext_vector_type(2)));
typedef _Float16 h8f __attribute__((ext_vector_type(8)));

// ---------------- workspace layout (float slots) ----------------
constexpr size_t OFF_WVH2 = 0;         // [76][608] h2f: cols 0..149 Wv rows, 150..599 Whh rows, pads 0
constexpr size_t OFF_WGF2 = 46208;     // [128][512] h2f folded Wg cc-part
constexpr size_t OFF_WIH2 = 111744;    // [256][452] h2f Wih (cols 450,451 zero)
constexpr size_t OFF_WPF  = 227456;    // [150][256] f32 folded Wp
constexpr size_t OFF_WQF  = 265856;    // [150][256] f32 folded Wq
constexpr size_t OFF_WUQ  = 304256;    // [64][64][150] f32 Wuq[q][b][h]
constexpr size_t OFF_P1   = 918656;    // [500][64][150] f32  (WG1 [512][256] f32 ALIASED here pre-P1)
constexpr size_t OFF_WG1  = OFF_P1;    // alias: consumed by Gu GEMM before P1 GEMM overwrites
constexpr size_t OFF_GUH  = 5718656;   // [500][64][512] f16 Gu
constexpr size_t OFF_UPT  = 13910656;  // [500][256][64] f32
constexpr size_t OFF_UQT  = 22102656;  // [64][256][64] f32   (UqT2 [64][32][256] h2f ALIASED post-GEMM)
constexpr size_t OFF_UQT2 = OFF_UQT;
constexpr size_t WS_FLOATS = 23151232; // 92.6 MB

// ---------------- helpers ----------------
__device__ __forceinline__ float fast_rcp(float x) { return __builtin_amdgcn_rcpf(x); }
__device__ __forceinline__ float sigm(float x)   { return fast_rcp(1.f + __expf(-x)); }
__device__ __forceinline__ float tanh_f(float x) { return 1.f - 2.f * fast_rcp(1.f + __expf(2.f * x)); }

// ---------------- precompute: weight folds + f16 column-major packs ----------------
__global__ __launch_bounds__(256) void k_prep(const float* __restrict__ Wp, const float* __restrict__ Wq,
                                              const float* __restrict__ Wg, const float* __restrict__ Wv,
                                              const float* __restrict__ Whh, const float* __restrict__ Wih,
                                              float* __restrict__ ws) {
    int i = blockIdx.x * 256 + threadIdx.x;
    if (i < 46208) {  // WVH2 [76][608]
        int k2 = i / 608, m = i - k2 * 608;
        float lo = 0.f, hi = 0.f;
        if (k2 < 75 && m < 600) {
            if (m < 150) { lo = Wv[m * 150 + 2 * k2]; hi = Wv[m * 150 + 2 * k2 + 1]; }
            else { int mm = m - 150; lo = Whh[mm * 150 + 2 * k2]; hi = Whh[mm * 150 + 2 * k2 + 1]; }
        }
        ((h2f*)(ws + OFF_WVH2))[i] = h2f{(_Float16)lo, (_Float16)hi};
        return;
    }
    i -= 46208;
    if (i < 65536) {  // WGF2 [128][512]
        int k2 = i >> 9, j = i & 511;
        int d = 2 * k2;
        size_t r = (size_t)(512 + j) * 1024;
        float lo = Wg[r + 512 + d] + Wg[r + 768 + d];
        float hi = Wg[r + 512 + d + 1] + Wg[r + 768 + d + 1];
        ((h2f*)(ws + OFF_WGF2))[i] = h2f{(_Float16)lo, (_Float16)hi};
        return;
    }
    i -= 65536;
    if (i < 115712) {  // WIH2 [256][452]
        int k2 = i / 452, m = i - k2 * 452;
        float lo = 0.f, hi = 0.f;
        if (m < 450) { lo = Wih[m * 512 + 2 * k2]; hi = Wih[m * 512 + 2 * k2 + 1]; }
        ((h2f*)(ws + OFF_WIH2))[i] = h2f{(_Float16)lo, (_Float16)hi};
        return;
    }
    i -= 115712;
    if (i < 38400) { int h = i >> 8, d = i & 255; ws[OFF_WPF + i] = Wp[h * 512 + d] + Wp[h * 512 + 256 + d]; return; }
    i -= 38400;
    if (i < 38400) { int h = i >> 8, d = i & 255; ws[OFF_WQF + i] = Wq[h * 512 + d] + Wq[h * 512 + 256 + d]; return; }
    i -= 38400;
    if (i < 131072) { int j = i >> 8, d = i & 255; size_t r = (size_t)(512 + j) * 1024; ws[OFF_WG1 + i] = Wg[r + d] + Wg[r + 256 + d]; return; }
}

// transpose X[t][64][256] -> XT[t][256][64], one block per t
__global__ __launch_bounds__(256) void k_tr(const float* __restrict__ X, float* __restrict__ XT) {
    __shared__ float tile[64][65];
    size_t base = (size_t)blockIdx.x * 16384;
    for (int ph = 0; ph < 4; ++ph) {
        for (int i = threadIdx.x; i < 4096; i += 256) {
            int b = i >> 6, dl = i & 63;
            tile[b][dl] = X[base + (size_t)b * 256 + ph * 64 + dl];
        }
        __syncthreads();
        for (int i = threadIdx.x; i < 4096; i += 256) {
            int d = i >> 6, bl = i & 63;
            XT[base + (size_t)(ph * 64 + d) * 64 + bl] = tile[bl][d];
        }
        __syncthreads();
    }
}

// acc[h,b] = sum_d XT[t,d,b]*Wf[h,d]; writes out[t][b][Hrows] as f32 or f16
__global__ __launch_bounds__(256) void k_gemm(const float* __restrict__ XT, const float* __restrict__ Wf,
                                              float* __restrict__ outF, _Float16* __restrict__ outH,
                                              int Hrows, int tilesPerT) {
    __shared__ float OL[64 * 33];
    int bidx = blockIdx.x;
    int t = bidx / tilesPerT, tile = bidx - t * tilesPerT;
    int w = threadIdx.x >> 6, lane = threadIdx.x & 63;
    int h0 = __builtin_amdgcn_readfirstlane(tile * 32 + w * 8);
    const float* x = XT + (size_t)t * 16384;
    float acc[8];
    const float* wr[8];
#pragma unroll
    for (int r = 0; r < 8; ++r) {
        int hr = h0 + r; if (hr >= Hrows) hr = Hrows - 1;
        wr[r] = Wf + (size_t)hr * 256;
        acc[r] = 0.f;
    }
    for (int d = 0; d < 256; d += 4) {
        float cv0 = x[(d + 0) * 64 + lane];
        float cv1 = x[(d + 1) * 64 + lane];
        float cv2 = x[(d + 2) * 64 + lane];
        float cv3 = x[(d + 3) * 64 + lane];
#pragma unroll
        for (int r = 0; r < 8; ++r) {
            float4 wv = *(const float4*)(wr[r] + d);
            acc[r] += cv0 * wv.x + cv1 * wv.y + cv2 * wv.z + cv3 * wv.w;
        }
    }
#pragma unroll
    for (int r = 0; r < 8; ++r) { int hl = w * 8 + r; OL[lane * 33 + hl] = acc[r]; }
    __syncthreads();
    int hbase = tile * 32;
    int nh = Hrows - hbase; if (nh > 32) nh = 32;
    for (int i = threadIdx.x; i < 64 * nh; i += 256) {
        int b = i / nh, hl = i - b * nh;
        float val = OL[b * 33 + hl];
        size_t idx = (size_t)t * 64 * Hrows + (size_t)b * Hrows + hbase + hl;
        if (outF) outF[idx] = val;
        else outH[idx] = (_Float16)val;
    }
}

// UqT2[b][q2][d] = (f16 Uq[2q2][b][d], f16 Uq[2q2+1][b][d])
__global__ __launch_bounds__(256) void k_uqt(const float* __restrict__ Uq, h2f* __restrict__ UqT2) {
    int b = blockIdx.x, d = threadIdx.x;
    for (int q2 = 0; q2 < 32; ++q2) {
        float lo = Uq[(size_t)(2 * q2) * 16384 + b * 256 + d];
        float hi = Uq[(size_t)(2 * q2 + 1) * 16384 + b * 256 + d];
        UqT2[(size_t)b * 8192 + q2 * 256 + d] = h2f{(_Float16)lo, (_Float16)hi};
    }
}

// ---------------- per-batch persistent scan: 64 blocks x 1024 threads ----------------
// EXACT copy of R3's k_scan3 (hardware-PASSED) with ONE change: the wgr[16]
// register preload is deleted; phase 3 streams Wgf2 from L2 with the same
// indices ((p3_ks*16+i)*512 + 4*p3_mq). This removes R3's spill traffic
// (WRITE_SIZE 42MB -> expect ~20MB) and is the correctness bisect vs R4/R5's
// failing 512-thread remap.
__global__ __launch_bounds__(1024) void k_scan6(
    const float* __restrict__ V, const float* __restrict__ v0,
    const float* __restrict__ bih, const float* __restrict__ bhh,
    const float* __restrict__ ws, float* __restrict__ out) {
    __shared__ __attribute__((aligned(16))) float red[4096];      // partial-sum scratch (16KB), reused per phase
    __shared__ __attribute__((aligned(16))) _Float16 wuqh[64 * 152];
    __shared__ __attribute__((aligned(16))) _Float16 vh[152];     // v_t f16 (k-padded: [150],[151]=0)
    __shared__ float pbf[152];
    __shared__ float ghf[452];
    __shared__ float Vb[152];
    __shared__ float bihL[452];
    __shared__ float bhhL[452];
    __shared__ float vf[152];
    __shared__ float sa[64];
    __shared__ __attribute__((aligned(8))) h2f sah[32];
    __shared__ float ccf[256];
    __shared__ __attribute__((aligned(8))) h2f cchp[128];
    __shared__ __attribute__((aligned(8))) h2f c_p[256];
    __shared__ float gif[452];

    const int tid = threadIdx.x, b = blockIdx.x;
    const int lane = tid & 63;
    const h2f* Wvh2 = (const h2f*)(ws + OFF_WVH2);
    const h2f* Wgf2 = (const h2f*)(ws + OFF_WGF2);
    const h2f* Wih2 = (const h2f*)(ws + OFF_WIH2);
    const h2f* UqT2b = (const h2f*)(ws + OFF_UQT2) + (size_t)b * 8192;
    const float* WuqG = ws + OFF_WUQ;
    const float* P1 = ws + OFF_P1;
    const _Float16* GuH = (const _Float16*)(ws + OFF_GUH);

    // ---- per-phase static thread assignments (identical to R3's k_scan3) ----
    // phase1: M=608 (600 live), M4=152, ks=4, 19 k2 each
    const int p1_ks = tid / 152, p1_mq = tid - p1_ks * 152;      // valid when tid<608
    const h2f* wv_base = Wvh2 + (size_t)(p1_ks * 19) * 608 + 4 * p1_mq;
    // phase2b: M=256, M4=64, ks=8, 4 q2 each
    const int p2_mq = tid & 63, p2_qs = tid >> 6;                 // valid when tid<512
    const h2f* uq_base = UqT2b + (size_t)(p2_qs * 4) * 256 + 4 * p2_mq;
    // phase3: M=512, M4=128, ks=8, 16 k2 each — h8f stream from L2
    const int p3_mq = tid & 127, p3_ks = tid >> 7;
    const h2f* wg_base = Wgf2 + (size_t)(p3_ks * 16) * 512 + 4 * p3_mq;
    // phase4: M=452 (450 live), M4=113, ks=8, 32 k2 each
    const int p4_ks = tid / 113, p4_mq = tid - p4_ks * 113;       // valid when tid<904
    const h2f* wih_base = Wih2 + (size_t)(p4_ks * 32) * 452 + 4 * p4_mq;

    // ---- one-time per-b LDS init ----
    for (int i = tid; i < 64 * 150; i += 1024) { int q = i / 150, h = i - q * 150; wuqh[q * 152 + h] = (_Float16)WuqG[(size_t)q * 9600 + b * 150 + h]; }
    for (int i = tid; i < 150; i += 1024) { Vb[i] = V[b * 150 + i]; float v = v0[b * 150 + i]; vf[i] = v; vh[i] = (_Float16)v; }
    for (int i = tid; i < 450; i += 1024) { bihL[i] = bih[i]; bhhL[i] = bhh[i]; }
    if (tid < 2) vh[150 + tid] = (_Float16)0.f;
    __syncthreads();

    for (int t = 0; t < LP; ++t) {
        // ---- phase1 partials: 608 threads, [pb|gh](m) = sum_k Wvh[k][m]*v[k] ----
        if (tid < 608) {
            const h2f* vh2 = (const h2f*)vh;
            float a0 = 0.f, a1 = 0.f, a2 = 0.f, a3 = 0.f;
#pragma unroll
            for (int i = 0; i < 19; ++i) {
                h8f w = *(const h8f*)(wv_base + (size_t)i * 608);
                h2f x = vh2[p1_ks * 19 + i];
                a0 = __builtin_amdgcn_fdot2(h2f{w[0], w[1]}, x, a0, false);
                a1 = __builtin_amdgcn_fdot2(h2f{w[2], w[3]}, x, a1, false);
                a2 = __builtin_amdgcn_fdot2(h2f{w[4], w[5]}, x, a2, false);
                a3 = __builtin_amdgcn_fdot2(h2f{w[6], w[7]}, x, a3, false);
            }
            *(float4*)(red + p1_ks * 608 + 4 * p1_mq) = float4{a0, a1, a2, a3};
        }
        __syncthreads();
        if (tid < 600) {  // reduce + epilogue
            float s = red[tid] + red[608 + tid] + red[1216 + tid] + red[1824 + tid];
            if (tid < 150) pbf[tid] = s + P1[(size_t)t * 9600 + b * 150 + tid];
            else ghf[tid - 150] = s + bhhL[tid - 150];
        }
        __syncthreads();
        // ---- phase2a: s[q] = sum_h tanh(pb+wuq)*V, 16 waves x 4 q ----
        {
            int w16 = tid >> 6;
#pragma unroll
            for (int i = 0; i < 4; ++i) {
                int q = w16 * 4 + i;
                float part = 0.f;
                for (int idx = lane; idx < 150; idx += 64)
                    part += tanh_f(pbf[idx] + (float)wuqh[q * 152 + idx]) * Vb[idx];
                part += __shfl_xor(part, 32); part += __shfl_xor(part, 16);
                part += __shfl_xor(part, 8);  part += __shfl_xor(part, 4);
                part += __shfl_xor(part, 2);  part += __shfl_xor(part, 1);
                if (lane == 0) sa[q] = part;
            }
        }
        __syncthreads();
        if (tid < 64) {  // softmax + pack a into h2f pairs
            float s = sa[tid];
            float m = s;
            m = fmaxf(m, __shfl_xor(m, 32)); m = fmaxf(m, __shfl_xor(m, 16));
            m = fmaxf(m, __shfl_xor(m, 8));  m = fmaxf(m, __shfl_xor(m, 4));
            m = fmaxf(m, __shfl_xor(m, 2));  m = fmaxf(m, __shfl_xor(m, 1));
            float e = __expf(s - m);
            float su = e;
            su += __shfl_xor(su, 32); su += __shfl_xor(su, 16); su += __shfl_xor(su, 8);
            su += __shfl_xor(su, 4);  su += __shfl_xor(su, 2);  su += __shfl_xor(su, 1);
            float a = e * fast_rcp(su);
            float an = __shfl_xor(a, 1);
            if ((tid & 1) == 0) sah[tid >> 1] = h2f{(_Float16)a, (_Float16)an};
        }
        __syncthreads();
        // ---- phase2b: cc[d] = sum_q a[q] Uq[q,b,d], 512 threads ----
        if (tid < 512) {
            float a0 = 0.f, a1 = 0.f, a2 = 0.f, a3 = 0.f;
#pragma unroll
            for (int i = 0; i < 4; ++i) {
                h8f u = *(const h8f*)(uq_base + (size_t)i * 256);
                h2f ap = sah[p2_qs * 4 + i];
                a0 = __builtin_amdgcn_fdot2(h2f{u[0], u[1]}, ap, a0, false);
                a1 = __builtin_amdgcn_fdot2(h2f{u[2], u[3]}, ap, a1, false);
                a2 = __builtin_amdgcn_fdot2(h2f{u[4], u[5]}, ap, a2, false);
                a3 = __builtin_amdgcn_fdot2(h2f{u[6], u[7]}, ap, a3, false);
            }
            *(float4*)(red + p2_qs * 256 + 4 * p2_mq) = float4{a0, a1, a2, a3};
        }
        __syncthreads();
        if (tid < 256) {
            float cc = 0.f;
#pragma unroll
            for (int s8 = 0; s8 < 8; ++s8) cc += red[s8 * 256 + tid];
            ccf[tid] = cc;
            float cn = __shfl_xor(cc, 1);
            if ((tid & 1) == 0) cchp[tid >> 1] = h2f{(_Float16)cc, (_Float16)cn};
        }
        __syncthreads();
        // ---- phase3: g-partials, h8f stream of Wgf2 from L2 (was wgr registers) ----
        {
            float a0 = 0.f, a1 = 0.f, a2 = 0.f, a3 = 0.f;
#pragma unroll
            for (int i = 0; i < 16; ++i) {
                h8f w = *(const h8f*)(wg_base + (size_t)i * 512);
                h2f cp = cchp[p3_ks * 16 + i];
                a0 = __builtin_amdgcn_fdot2(h2f{w[0], w[1]}, cp, a0, false);
                a1 = __builtin_amdgcn_fdot2(h2f{w[2], w[3]}, cp, a1, false);
                a2 = __builtin_amdgcn_fdot2(h2f{w[4], w[5]}, cp, a2, false);
                a3 = __builtin_amdgcn_fdot2(h2f{w[6], w[7]}, cp, a3, false);
            }
            *(float4*)(red + p3_ks * 512 + 4 * p3_mq) = float4{a0, a1, a2, a3};
        }
        __syncthreads();
        if (tid < 512) {  // g reduce + c_ pack
            float s = (float)GuH[(size_t)t * 32768 + b * 512 + tid];
#pragma unroll
            for (int s8 = 0; s8 < 8; ++s8) s += red[s8 * 512 + tid];
            float val = sigm(s) * ccf[tid & 255];
            float vn2 = __shfl_xor(val, 1);
            if ((tid & 1) == 0) c_p[tid >> 1] = h2f{(_Float16)val, (_Float16)vn2};
        }
        __syncthreads();
        // ---- phase4: gi partials, 904 threads ----
        if (tid < 904) {
            float a0 = 0.f, a1 = 0.f, a2 = 0.f, a3 = 0.f;
#pragma unroll
            for (int i = 0; i < 32; ++i) {
                h8f w = *(const h8f*)(wih_base + (size_t)i * 452);
                h2f cp = c_p[p4_ks * 32 + i];
                a0 = __builtin_amdgcn_fdot2(h2f{w[0], w[1]}, cp, a0, false);
                a1 = __builtin_amdgcn_fdot2(h2f{w[2], w[3]}, cp, a1, false);
                a2 = __builtin_amdgcn_fdot2(h2f{w[4], w[5]}, cp, a2, false);
                a3 = __builtin_amdgcn_fdot2(h2f{w[6], w[7]}, cp, a3, false);
            }
            *(float4*)(red + p4_ks * 456 + 4 * p4_mq) = float4{a0, a1, a2, a3};
        }
        __syncthreads();
        if (tid < 450) {
            float s = 0.f;
#pragma unroll
            for (int s8 = 0; s8 < 8; ++s8) s += red[s8 * 456 + tid];
            gif[tid] = s;
        }
        __syncthreads();
        if (tid < 150) {  // GRU combine + state update + output
            float r = sigm(gif[tid] + bihL[tid] + ghf[tid]);
            float z = sigm(gif[150 + tid] + bihL[150 + tid] + ghf[150 + tid]);
            float n = tanh_f(gif[300 + tid] + bihL[300 + tid] + r * ghf[300 + tid]);
            float vn = (1.f - z) * n + z * vf[tid];
            vf[tid] = vn;
            vh[tid] = (_Float16)vn;
            out[(size_t)t * 9600 + b * 150 + tid] = vn;
        }
        __syncthreads();
    }
}

// ---------------- launch ----------------
extern "C" void kernel_launch(void* const* d_in, const int* in_sizes, int n_in,
                              void* d_out, int out_size, void* d_ws, size_t ws_size,
                              hipStream_t stream) {
    const float* Up  = (const float*)d_in[0];
    const float* Uq  = (const float*)d_in[1];
    const float* Wp  = (const float*)d_in[2];
    const float* Wq  = (const float*)d_in[3];
    const float* Wv  = (const float*)d_in[4];
    const float* Wg  = (const float*)d_in[5];
    const float* V   = (const float*)d_in[6];
    const float* v0  = (const float*)d_in[7];
    const float* Wih = (const float*)d_in[8];
    const float* Whh = (const float*)d_in[9];
    const float* bih = (const float*)d_in[10];
    const float* bhh = (const float*)d_in[11];
    float* out = (float*)d_out;
    float* ws = (float*)d_ws;

    if (ws_size < WS_FLOATS * sizeof(float)) return;

    k_prep<<<1701, 256, 0, stream>>>(Wp, Wq, Wg, Wv, Whh, Wih, ws);
    k_tr<<<500, 256, 0, stream>>>(Up, ws + OFF_UPT);
    k_tr<<<64, 256, 0, stream>>>(Uq, ws + OFF_UQT);
    // Gu[t][b][j] = Up[t] @ Wg1^T (f16) — before P1 GEMM (WG1 aliases P1)
    k_gemm<<<8000, 256, 0, stream>>>(ws + OFF_UPT, ws + OFF_WG1, nullptr, (_Float16*)(ws + OFF_GUH), 512, 16);
    // P1[t][b][h] = Up[t] @ Wpf^T (f32)
    k_gemm<<<2500, 256, 0, stream>>>(ws + OFF_UPT, ws + OFF_WPF, ws + OFF_P1, nullptr, 150, 5);
    // Wuq[q][b][h] = Uq[q] @ Wqf^T (f32) — consumes UQT before k_uqt overwrites
    k_gemm<<<320, 256, 0, stream>>>(ws + OFF_UQT, ws + OFF_WQF, ws + OFF_WUQ, nullptr, 150, 5);
    // UqT2[b][q2][d] f16 pairs — aliases UQT (safe after Wuq GEMM)
    k_uqt<<<64, 256, 0, stream>>>(Uq, (h2f*)(ws + OFF_UQT2));
    // barrier-free per-batch scan (R3 structure, phase3 streams from L2)
    k_scan6<<<64, 1024, 0, stream>>>(V, v0, bih, bhh, ws, out);
}

// Round 7
// 7459.935 us; speedup vs baseline: 1.4226x; 1.4053x over previous
//
#include <hip/hip_runtime.h>
#include <hip/hip_fp16.h>

// LP=500, LQ=64, B=64, D=256, H=150
#define LP 500

typedef _Float16 h2f __attribute__((ext_vector_type(2)));
typedef _Float16 h8f __attribute__((ext_vector_type(8)));

// ---------------- workspace layout (float slots) ----------------
constexpr size_t OFF_WVH2 = 0;         // [76][608] h2f: cols 0..149 Wv rows, 150..599 Whh rows, pads 0
constexpr size_t OFF_WGF2 = 46208;     // [128][512] h2f folded Wg cc-part
constexpr size_t OFF_WIH2 = 111744;    // [256][452] h2f Wih (cols 450,451 zero)
constexpr size_t OFF_WPF  = 227456;    // [150][256] f32 folded Wp
constexpr size_t OFF_WQF  = 265856;    // [150][256] f32 folded Wq
constexpr size_t OFF_WUQ  = 304256;    // [64][64][150] f32 Wuq[q][b][h]
constexpr size_t OFF_P1   = 918656;    // [500][64][150] f32  (WG1 [512][256] f32 ALIASED here pre-P1)
constexpr size_t OFF_WG1  = OFF_P1;    // alias: consumed by Gu GEMM before P1 GEMM overwrites
constexpr size_t OFF_GUH  = 5718656;   // [500][64][512] f16 Gu
constexpr size_t OFF_UPT  = 13910656;  // [500][256][64] f32
constexpr size_t OFF_UQT  = 22102656;  // [64][256][64] f32   (UqT2 [64][32][256] h2f ALIASED post-GEMM)
constexpr size_t OFF_UQT2 = OFF_UQT;
constexpr size_t WS_FLOATS = 23151232; // 92.6 MB

// ---------------- helpers ----------------
__device__ __forceinline__ float fast_rcp(float x) { return __builtin_amdgcn_rcpf(x); }
__device__ __forceinline__ float sigm(float x)   { return fast_rcp(1.f + __expf(-x)); }
__device__ __forceinline__ float tanh_f(float x) { return 1.f - 2.f * fast_rcp(1.f + __expf(2.f * x)); }

// ---------------- precompute: weight folds + f16 column-major packs ----------------
__global__ __launch_bounds__(256) void k_prep(const float* __restrict__ Wp, const float* __restrict__ Wq,
                                              const float* __restrict__ Wg, const float* __restrict__ Wv,
                                              const float* __restrict__ Whh, const float* __restrict__ Wih,
                                              float* __restrict__ ws) {
    int i = blockIdx.x * 256 + threadIdx.x;
    if (i < 46208) {  // WVH2 [76][608]
        int k2 = i / 608, m = i - k2 * 608;
        float lo = 0.f, hi = 0.f;
        if (k2 < 75 && m < 600) {
            if (m < 150) { lo = Wv[m * 150 + 2 * k2]; hi = Wv[m * 150 + 2 * k2 + 1]; }
            else { int mm = m - 150; lo = Whh[mm * 150 + 2 * k2]; hi = Whh[mm * 150 + 2 * k2 + 1]; }
        }
        ((h2f*)(ws + OFF_WVH2))[i] = h2f{(_Float16)lo, (_Float16)hi};
        return;
    }
    i -= 46208;
    if (i < 65536) {  // WGF2 [128][512]
        int k2 = i >> 9, j = i & 511;
        int d = 2 * k2;
        size_t r = (size_t)(512 + j) * 1024;
        float lo = Wg[r + 512 + d] + Wg[r + 768 + d];
        float hi = Wg[r + 512 + d + 1] + Wg[r + 768 + d + 1];
        ((h2f*)(ws + OFF_WGF2))[i] = h2f{(_Float16)lo, (_Float16)hi};
        return;
    }
    i -= 65536;
    if (i < 115712) {  // WIH2 [256][452]
        int k2 = i / 452, m = i - k2 * 452;
        float lo = 0.f, hi = 0.f;
        if (m < 450) { lo = Wih[m * 512 + 2 * k2]; hi = Wih[m * 512 + 2 * k2 + 1]; }
        ((h2f*)(ws + OFF_WIH2))[i] = h2f{(_Float16)lo, (_Float16)hi};
        return;
    }
    i -= 115712;
    if (i < 38400) { int h = i >> 8, d = i & 255; ws[OFF_WPF + i] = Wp[h * 512 + d] + Wp[h * 512 + 256 + d]; return; }
    i -= 38400;
    if (i < 38400) { int h = i >> 8, d = i & 255; ws[OFF_WQF + i] = Wq[h * 512 + d] + Wq[h * 512 + 256 + d]; return; }
    i -= 38400;
    if (i < 131072) { int j = i >> 8, d = i & 255; size_t r = (size_t)(512 + j) * 1024; ws[OFF_WG1 + i] = Wg[r + d] + Wg[r + 256 + d]; return; }
}

// transpose X[t][64][256] -> XT[t][256][64], one block per t
__global__ __launch_bounds__(256) void k_tr(const float* __restrict__ X, float* __restrict__ XT) {
    __shared__ float tile[64][65];
    size_t base = (size_t)blockIdx.x * 16384;
    for (int ph = 0; ph < 4; ++ph) {
        for (int i = threadIdx.x; i < 4096; i += 256) {
            int b = i >> 6, dl = i & 63;
            tile[b][dl] = X[base + (size_t)b * 256 + ph * 64 + dl];
        }
        __syncthreads();
        for (int i = threadIdx.x; i < 4096; i += 256) {
            int d = i >> 6, bl = i & 63;
            XT[base + (size_t)(ph * 64 + d) * 64 + bl] = tile[bl][d];
        }
        __syncthreads();
    }
}

// acc[h,b] = sum_d XT[t,d,b]*Wf[h,d]; writes out[t][b][Hrows] as f32 or f16
__global__ __launch_bounds__(256) void k_gemm(const float* __restrict__ XT, const float* __restrict__ Wf,
                                              float* __restrict__ outF, _Float16* __restrict__ outH,
                                              int Hrows, int tilesPerT) {
    __shared__ float OL[64 * 33];
    int bidx = blockIdx.x;
    int t = bidx / tilesPerT, tile = bidx - t * tilesPerT;
    int w = threadIdx.x >> 6, lane = threadIdx.x & 63;
    int h0 = __builtin_amdgcn_readfirstlane(tile * 32 + w * 8);
    const float* x = XT + (size_t)t * 16384;
    float acc[8];
    const float* wr[8];
#pragma unroll
    for (int r = 0; r < 8; ++r) {
        int hr = h0 + r; if (hr >= Hrows) hr = Hrows - 1;
        wr[r] = Wf + (size_t)hr * 256;
        acc[r] = 0.f;
    }
    for (int d = 0; d < 256; d += 4) {
        float cv0 = x[(d + 0) * 64 + lane];
        float cv1 = x[(d + 1) * 64 + lane];
        float cv2 = x[(d + 2) * 64 + lane];
        float cv3 = x[(d + 3) * 64 + lane];
#pragma unroll
        for (int r = 0; r < 8; ++r) {
            float4 wv = *(const float4*)(wr[r] + d);
            acc[r] += cv0 * wv.x + cv1 * wv.y + cv2 * wv.z + cv3 * wv.w;
        }
    }
#pragma unroll
    for (int r = 0; r < 8; ++r) { int hl = w * 8 + r; OL[lane * 33 + hl] = acc[r]; }
    __syncthreads();
    int hbase = tile * 32;
    int nh = Hrows - hbase; if (nh > 32) nh = 32;
    for (int i = threadIdx.x; i < 64 * nh; i += 256) {
        int b = i / nh, hl = i - b * nh;
        float val = OL[b * 33 + hl];
        size_t idx = (size_t)t * 64 * Hrows + (size_t)b * Hrows + hbase + hl;
        if (outF) outF[idx] = val;
        else outH[idx] = (_Float16)val;
    }
}

// UqT2[b][q2][d] = (f16 Uq[2q2][b][d], f16 Uq[2q2+1][b][d])
__global__ __launch_bounds__(256) void k_uqt(const float* __restrict__ Uq, h2f* __restrict__ UqT2) {
    int b = blockIdx.x, d = threadIdx.x;
    for (int q2 = 0; q2 < 32; ++q2) {
        float lo = Uq[(size_t)(2 * q2) * 16384 + b * 256 + d];
        float hi = Uq[(size_t)(2 * q2 + 1) * 16384 + b * 256 + d];
        UqT2[(size_t)b * 8192 + q2 * 256 + d] = h2f{(_Float16)lo, (_Float16)hi};
    }
}

// ---------------- per-batch persistent scan: 64 blocks x 512 threads ----------------
// __launch_bounds__(512,2): 8 waves = 2/SIMD -> 256-VGPR budget. wgr[32]
// (all of Wgf2, 128 VGPR/thread across 512 threads = 262KB, no duplication)
// is register-resident. R4/R5's failure was the phase1 reduce guard
// (tid<600 with 512 threads left ghf[362..449] unwritten) — fixed with a
// strided loop below.
__global__ __launch_bounds__(512, 2) void k_scan7(
    const float* __restrict__ V, const float* __restrict__ v0,
    const float* __restrict__ bih, const float* __restrict__ bhh,
    const float* __restrict__ ws, float* __restrict__ out) {
    __shared__ __attribute__((aligned(16))) float red[2048];
    __shared__ __attribute__((aligned(16))) _Float16 wuqh[64 * 152];
    __shared__ __attribute__((aligned(16))) _Float16 vh[152];
    __shared__ float pbf[152];
    __shared__ float ghf[452];
    __shared__ float Vb[152];
    __shared__ float bihL[452];
    __shared__ float bhhL[452];
    __shared__ float vf[152];
    __shared__ float sa[64];
    __shared__ __attribute__((aligned(8))) h2f sah[32];
    __shared__ float ccf[256];
    __shared__ __attribute__((aligned(8))) h2f cchp[128];
    __shared__ __attribute__((aligned(8))) h2f c_p[256];
    __shared__ float gif[452];

    const int tid = threadIdx.x, b = blockIdx.x;
    const int lane = tid & 63;
    const h2f* Wvh2 = (const h2f*)(ws + OFF_WVH2);
    const h2f* Wgf2 = (const h2f*)(ws + OFF_WGF2);
    const h2f* Wih2 = (const h2f*)(ws + OFF_WIH2);
    const h2f* UqT2b = (const h2f*)(ws + OFF_UQT2) + (size_t)b * 8192;
    const float* WuqG = ws + OFF_WUQ;
    const float* P1 = ws + OFF_P1;
    const _Float16* GuH = (const _Float16*)(ws + OFF_GUH);

    // phase1: M=608(600 live), 152 quads x ks=3 (456 threads), 25 k2 each
    const int p1_ks = tid / 152, p1_mq = tid - p1_ks * 152;
    const h2f* wv_base = Wvh2 + (size_t)(p1_ks * 25) * 608 + 4 * p1_mq;
    // phase2b: 64 quads x ks=8 (512 threads), 4 q2 each
    const int p2_qs = tid >> 6, p2_mq = tid & 63;
    const h2f* uq_base = UqT2b + (size_t)(p2_qs * 4) * 256 + 4 * p2_mq;
    // phase3: 128 quads x ks=4 (512 threads), 32 k2 each — REGISTER weights
    const int p3_ks = tid >> 7, p3_mq = tid & 127;
    // phase4: M=452(450 live), 113 quads x ks=4 (452 threads), 64 k2 each
    const int p4_ks = tid / 113, p4_mq = tid - p4_ks * 113;
    const h2f* wih_base = Wih2 + (size_t)(p4_ks * 64) * 452 + 4 * p4_mq;

    // register-resident Wgf2: 512 threads x 32 h8f = 262KB
    h8f wgr[32];
#pragma unroll
    for (int i = 0; i < 32; ++i)
        wgr[i] = *(const h8f*)(Wgf2 + (size_t)(p3_ks * 32 + i) * 512 + 4 * p3_mq);

    // one-time per-b LDS init
    for (int i = tid; i < 64 * 150; i += 512) { int q = i / 150, h = i - q * 150; wuqh[q * 152 + h] = (_Float16)WuqG[(size_t)q * 9600 + b * 150 + h]; }
    for (int i = tid; i < 150; i += 512) { Vb[i] = V[b * 150 + i]; float v = v0[b * 150 + i]; vf[i] = v; vh[i] = (_Float16)v; }
    for (int i = tid; i < 450; i += 512) { bihL[i] = bih[i]; bhhL[i] = bhh[i]; }
    if (tid < 2) vh[150 + tid] = (_Float16)0.f;
    __syncthreads();

    for (int t = 0; t < LP; ++t) {
        // ---- prefetch this step's HBM-resident per-step data (off critical path) ----
        float p1v = 0.f;
        if (tid < 150) p1v = P1[(size_t)t * 9600 + b * 150 + tid];
        float guv = (float)GuH[(size_t)t * 32768 + b * 512 + tid];

        // ---- phase1: [pb|gh](m) partials = sum_k Wvh[k][m]*v[k] ----
        if (tid < 456) {
            const h2f* vh2 = (const h2f*)vh;
            float a0 = 0.f, a1 = 0.f, a2 = 0.f, a3 = 0.f;
#pragma unroll 5
            for (int i = 0; i < 25; ++i) {
                h8f w = *(const h8f*)(wv_base + (size_t)i * 608);
                h2f x = vh2[p1_ks * 25 + i];
                a0 = __builtin_amdgcn_fdot2(h2f{w[0], w[1]}, x, a0, false);
                a1 = __builtin_amdgcn_fdot2(h2f{w[2], w[3]}, x, a1, false);
                a2 = __builtin_amdgcn_fdot2(h2f{w[4], w[5]}, x, a2, false);
                a3 = __builtin_amdgcn_fdot2(h2f{w[6], w[7]}, x, a3, false);
            }
            *(float4*)(red + p1_ks * 608 + 4 * p1_mq) = float4{a0, a1, a2, a3};
        }
        __syncthreads();
        // FIXED: 600 outputs with 512 threads -> strided loop (R4/R5 bug)
        for (int m = tid; m < 600; m += 512) {
            float s = red[m] + red[608 + m] + red[1216 + m];
            if (m < 150) pbf[m] = s + p1v;
            else ghf[m - 150] = s + bhhL[m - 150];
        }
        __syncthreads();
        // ---- phase2a: s[q] = sum_h tanh(pb+wuq)*V, 8 waves x 8 q ----
        {
            int w8 = tid >> 6;
#pragma unroll
            for (int i = 0; i < 8; ++i) {
                int q = w8 * 8 + i;
                float part = 0.f;
                for (int idx = lane; idx < 150; idx += 64)
                    part += tanh_f(pbf[idx] + (float)wuqh[q * 152 + idx]) * Vb[idx];
                part += __shfl_xor(part, 32); part += __shfl_xor(part, 16);
                part += __shfl_xor(part, 8);  part += __shfl_xor(part, 4);
                part += __shfl_xor(part, 2);  part += __shfl_xor(part, 1);
                if (lane == 0) sa[q] = part;
            }
        }
        __syncthreads();
        if (tid < 64) {  // softmax + pack a-pairs
            float s = sa[tid];
            float m = s;
            m = fmaxf(m, __shfl_xor(m, 32)); m = fmaxf(m, __shfl_xor(m, 16));
            m = fmaxf(m, __shfl_xor(m, 8));  m = fmaxf(m, __shfl_xor(m, 4));
            m = fmaxf(m, __shfl_xor(m, 2));  m = fmaxf(m, __shfl_xor(m, 1));
            float e = __expf(s - m);
            float su = e;
            su += __shfl_xor(su, 32); su += __shfl_xor(su, 16); su += __shfl_xor(su, 8);
            su += __shfl_xor(su, 4);  su += __shfl_xor(su, 2);  su += __shfl_xor(su, 1);
            float a = e * fast_rcp(su);
            float an = __shfl_xor(a, 1);
            if ((tid & 1) == 0) sah[tid >> 1] = h2f{(_Float16)a, (_Float16)an};
        }
        __syncthreads();
        // ---- phase2b: cc[d] partials = sum_q a[q] Uq[q,b,d] ----
        {
            float a0 = 0.f, a1 = 0.f, a2 = 0.f, a3 = 0.f;
#pragma unroll
            for (int i = 0; i < 4; ++i) {
                h8f u = *(const h8f*)(uq_base + (size_t)i * 256);
                h2f ap = sah[p2_qs * 4 + i];
                a0 = __builtin_amdgcn_fdot2(h2f{u[0], u[1]}, ap, a0, false);
                a1 = __builtin_amdgcn_fdot2(h2f{u[2], u[3]}, ap, a1, false);
                a2 = __builtin_amdgcn_fdot2(h2f{u[4], u[5]}, ap, a2, false);
                a3 = __builtin_amdgcn_fdot2(h2f{u[6], u[7]}, ap, a3, false);
            }
            *(float4*)(red + p2_qs * 256 + 4 * p2_mq) = float4{a0, a1, a2, a3};
        }
        __syncthreads();
        if (tid < 256) {  // cc reduce + pack cc-pairs
            float cc = 0.f;
#pragma unroll
            for (int s8 = 0; s8 < 8; ++s8) cc += red[s8 * 256 + tid];
            ccf[tid] = cc;
            float cn = __shfl_xor(cc, 1);
            if ((tid & 1) == 0) cchp[tid >> 1] = h2f{(_Float16)cc, (_Float16)cn};
        }
        __syncthreads();
        // ---- phase3: g partials from REGISTER-resident Wgf2 ----
        {
            float a0 = 0.f, a1 = 0.f, a2 = 0.f, a3 = 0.f;
#pragma unroll
            for (int i = 0; i < 32; ++i) {
                h2f cp = cchp[p3_ks * 32 + i];
                h8f w = wgr[i];
                a0 = __builtin_amdgcn_fdot2(h2f{w[0], w[1]}, cp, a0, false);
                a1 = __builtin_amdgcn_fdot2(h2f{w[2], w[3]}, cp, a1, false);
                a2 = __builtin_amdgcn_fdot2(h2f{w[4], w[5]}, cp, a2, false);
                a3 = __builtin_amdgcn_fdot2(h2f{w[6], w[7]}, cp, a3, false);
            }
            *(float4*)(red + p3_ks * 512 + 4 * p3_mq) = float4{a0, a1, a2, a3};
        }
        __syncthreads();
        {  // g reduce + c_ pack (512 outputs = 512 threads, j = tid)
            float s = guv;
#pragma unroll
            for (int s4 = 0; s4 < 4; ++s4) s += red[s4 * 512 + tid];
            float val = sigm(s) * ccf[tid & 255];
            float vn2 = __shfl_xor(val, 1);
            if ((tid & 1) == 0) c_p[tid >> 1] = h2f{(_Float16)val, (_Float16)vn2};
        }
        __syncthreads();
        // ---- phase4: gi partials, deep-batched h8f loads ----
        if (tid < 452) {
            float a0 = 0.f, a1 = 0.f, a2 = 0.f, a3 = 0.f;
#pragma unroll 16
            for (int i = 0; i < 64; ++i) {
                h8f w = *(const h8f*)(wih_base + (size_t)i * 452);
                h2f cp = c_p[p4_ks * 64 + i];
                a0 = __builtin_amdgcn_fdot2(h2f{w[0], w[1]}, cp, a0, false);
                a1 = __builtin_amdgcn_fdot2(h2f{w[2], w[3]}, cp, a1, false);
                a2 = __builtin_amdgcn_fdot2(h2f{w[4], w[5]}, cp, a2, false);
                a3 = __builtin_amdgcn_fdot2(h2f{w[6], w[7]}, cp, a3, false);
            }
            *(float4*)(red + p4_ks * 456 + 4 * p4_mq) = float4{a0, a1, a2, a3};
        }
        __syncthreads();
        if (tid < 450) {
            gif[tid] = red[tid] + red[456 + tid] + red[912 + tid] + red[1368 + tid];
        }
        __syncthreads();
        if (tid < 150) {  // GRU combine + state update + output
            float r = sigm(gif[tid] + bihL[tid] + ghf[tid]);
            float z = sigm(gif[150 + tid] + bihL[150 + tid] + ghf[150 + tid]);
            float n = tanh_f(gif[300 + tid] + bihL[300 + tid] + r * ghf[300 + tid]);
            float vn = (1.f - z) * n + z * vf[tid];
            vf[tid] = vn;
            vh[tid] = (_Float16)vn;
            out[(size_t)t * 9600 + b * 150 + tid] = vn;
        }
        __syncthreads();
    }
}

// ---------------- launch ----------------
extern "C" void kernel_launch(void* const* d_in, const int* in_sizes, int n_in,
                              void* d_out, int out_size, void* d_ws, size_t ws_size,
                              hipStream_t stream) {
    const float* Up  = (const float*)d_in[0];
    const float* Uq  = (const float*)d_in[1];
    const float* Wp  = (const float*)d_in[2];
    const float* Wq  = (const float*)d_in[3];
    const float* Wv  = (const float*)d_in[4];
    const float* Wg  = (const float*)d_in[5];
    const float* V   = (const float*)d_in[6];
    const float* v0  = (const float*)d_in[7];
    const float* Wih = (const float*)d_in[8];
    const float* Whh = (const float*)d_in[9];
    const float* bih = (const float*)d_in[10];
    const float* bhh = (const float*)d_in[11];
    float* out = (float*)d_out;
    float* ws = (float*)d_ws;

    if (ws_size < WS_FLOATS * sizeof(float)) return;

    k_prep<<<1701, 256, 0, stream>>>(Wp, Wq, Wg, Wv, Whh, Wih, ws);
    k_tr<<<500, 256, 0, stream>>>(Up, ws + OFF_UPT);
    k_tr<<<64, 256, 0, stream>>>(Uq, ws + OFF_UQT);
    // Gu[t][b][j] = Up[t] @ Wg1^T (f16) — before P1 GEMM (WG1 aliases P1)
    k_gemm<<<8000, 256, 0, stream>>>(ws + OFF_UPT, ws + OFF_WG1, nullptr, (_Float16*)(ws + OFF_GUH), 512, 16);
    // P1[t][b][h] = Up[t] @ Wpf^T (f32)
    k_gemm<<<2500, 256, 0, stream>>>(ws + OFF_UPT, ws + OFF_WPF, ws + OFF_P1, nullptr, 150, 5);
    // Wuq[q][b][h] = Uq[q] @ Wqf^T (f32) — consumes UQT before k_uqt overwrites
    k_gemm<<<320, 256, 0, stream>>>(ws + OFF_UQT, ws + OFF_WQF, ws + OFF_WUQ, nullptr, 150, 5);
    // UqT2[b][q2][d] f16 pairs — aliases UQT (safe after Wuq GEMM)
    k_uqt<<<64, 256, 0, stream>>>(Uq, (h2f*)(ws + OFF_UQT2));
    // barrier-free per-batch scan (512 thr, 256-VGPR budget, reg-resident Wgf2)
    k_scan7<<<64, 512, 0, stream>>>(V, v0, bih, bhh, ws, out);
}